// Round 1
// 498.411 us; speedup vs baseline: 1.0231x; 1.0231x over previous
//
#include <hip/hip_runtime.h>

#define B_  64
#define C_  256
#define CS  64
#define NC  8
#define HW  4096
#define BC  16384   // B_*C_

typedef float v4f __attribute__((ext_vector_type(4)));

// ALL tensors fp32 (x, w1, b1, w2, b2, act_range fp32; sample_cluster int32; out fp32).

// ---------------- Kernel 1: per-(b,c) plane sum/min/max over HW ----------------
// Regular (caching) loads on purpose: we WANT x resident in L3 for k_quant's re-read.
__global__ __launch_bounds__(256) void k_reduce(const float* __restrict__ x,
    float* __restrict__ sumb, float* __restrict__ minb, float* __restrict__ maxb){
  int p = blockIdx.x;
  int t = threadIdx.x;
  const float4* base = (const float4*)(x + (size_t)p * HW);
  float s = 0.f, mn = INFINITY, mx = -INFINITY;
  #pragma unroll
  for (int k = 0; k < 4; k++){
    float4 v = base[t + 256 * k];
    s += (v.x + v.y) + (v.z + v.w);
    mn = fminf(mn, fminf(fminf(v.x, v.y), fminf(v.z, v.w)));
    mx = fmaxf(mx, fmaxf(fmaxf(v.x, v.y), fmaxf(v.z, v.w)));
  }
  #pragma unroll
  for (int off = 1; off < 64; off <<= 1){
    s  += __shfl_xor(s, off, 64);
    mn  = fminf(mn, __shfl_xor(mn, off, 64));
    mx  = fmaxf(mx, __shfl_xor(mx, off, 64));
  }
  __shared__ float ls[4], lmn[4], lmx[4];
  int w = t >> 6;
  if ((t & 63) == 0){ ls[w] = s; lmn[w] = mn; lmx[w] = mx; }
  __syncthreads();
  if (t == 0){
    sumb[p] = ls[0] + ls[1] + ls[2] + ls[3];
    minb[p] = fminf(fminf(lmn[0], lmn[1]), fminf(lmn[2], lmn[3]));
    maxb[p] = fmaxf(fmaxf(lmx[0], lmx[1]), fmaxf(lmx[2], lmx[3]));
  }
}

// ---------------- Kernel 2a: per-sample MLP + hardsigmoid + sample min/max ----------------
// grid = 64 blocks (one per batch sample), 256 threads (one per channel c)
__global__ __launch_bounds__(256) void k_mlp(
    const float* __restrict__ sumb, const float* __restrict__ minb, const float* __restrict__ maxb,
    const float* __restrict__ w1, const float* __restrict__ b1,
    const float* __restrict__ w2, const float* __restrict__ b2,
    float* __restrict__ scaleb, float* __restrict__ sminb, float* __restrict__ smaxb){
  int b = blockIdx.x;
  int t = threadIdx.x;
  __shared__ float s_pool[C_];
  __shared__ float s_h[CS];
  __shared__ float lmn[4], lmx[4];

  s_pool[t] = sumb[b * C_ + t] * (1.0f / 4096.0f);   // pooled = sum/4096 (exact pow2)
  __syncthreads();

  if (t < CS){
    const float4* pw = (const float4*)(w1 + t * C_);
    const float4* pp = (const float4*)s_pool;
    float acc = 0.f;
    #pragma unroll
    for (int i = 0; i < 64; i++){
      float4 w = pw[i], p = pp[i];
      acc += p.x*w.x + p.y*w.y + p.z*w.z + p.w*w.w;
    }
    s_h[t] = fmaxf(acc + b1[t], 0.f);
  }
  __syncthreads();

  // channel c = t: scale = hardsigmoid(dot(h, w2[c]) + b2[c])
  const float4* pw2 = (const float4*)(w2 + t * CS);
  const float4* ph  = (const float4*)s_h;
  float acc = 0.f;
  #pragma unroll
  for (int i = 0; i < 16; i++){
    float4 w = pw2[i], h = ph[i];
    acc += h.x*w.x + h.y*w.y + h.z*w.z + h.w*w.w;
  }
  float v = acc + b2[t];
  float sc = fminf(fmaxf(v * (1.0f / 6.0f) + 0.5f, 0.f), 1.f);
  scaleb[b * C_ + t] = sc;

  // per-sample min/max of out = scale*x: scale>=0, fp32 mul monotone -> exact
  float mn = sc * minb[b * C_ + t];
  float mx = sc * maxb[b * C_ + t];
  #pragma unroll
  for (int off = 1; off < 64; off <<= 1){
    mn = fminf(mn, __shfl_xor(mn, off, 64));
    mx = fmaxf(mx, __shfl_xor(mx, off, 64));
  }
  int w = t >> 6;
  if ((t & 63) == 0){ lmn[w] = mn; lmx[w] = mx; }
  __syncthreads();
  if (t == 0){
    sminb[b] = fminf(fminf(lmn[0], lmn[1]), fminf(lmn[2], lmn[3]));
    smaxb[b] = fmaxf(fmaxf(lmx[0], lmx[1]), fmaxf(lmx[2], lmx[3]));
  }
}

// ---------------- Kernel 2b: cluster segment min/max + EMA + quant params ----------------
__global__ __launch_bounds__(64) void k_cluster(
    const float* __restrict__ sminb, const float* __restrict__ smaxb,
    const float* __restrict__ act_range, const int* __restrict__ clus,
    float* __restrict__ ssb, float* __restrict__ zzb){
  __shared__ float s_s[NC], s_z[NC];
  int t = threadIdx.x;
  if (t < NC){
    float cm = INFINITY, cM = -INFINITY;
    for (int b = 0; b < B_; b++){
      if (clus[b] == t){ cm = fminf(cm, sminb[b]); cM = fmaxf(cM, smaxb[b]); }
    }
    float nmin = act_range[2*t]     * 0.995f + cm * 0.005f;
    float nmax = act_range[2*t + 1] * 0.995f + cM * 0.005f;
    float sv = (nmax - nmin) / 255.0f;
    s_s[t] = sv;
    s_z[t] = -rintf(nmin / sv);          // rintf = round-half-even = jnp.round
  }
  __syncthreads();
  int k = clus[t];
  ssb[t] = s_s[k];
  zzb[t] = s_z[k];
}

// ---------------- Kernel 3: elementwise fake-quant (fp32 in -> fp32 out) ----------------
// L3-reuse engineering:
//  (a) REVERSE plane order: k_reduce streamed x[0..16383] through the 256 MiB L3;
//      the tail planes are the warmest. Read them first before they age out.
//  (b) NON-TEMPORAL stores for out: out is never re-read; nt keeps the 256 MiB
//      write stream from evicting the x lines we are about to read.
//  (c) divide -> one uniform reciprocal per block + FMA (flips only exact .5
//      boundary elements by +-1 quant step; absmax already sits at one step).
__global__ __launch_bounds__(256) void k_quant(const float* __restrict__ x,
    const float* __restrict__ scaleb, const float* __restrict__ ssb, const float* __restrict__ zzb,
    float* __restrict__ out){
  int p = (BC - 1) - blockIdx.x;     // reverse traversal
  int b = p >> 8;
  float sc = scaleb[p];
  float ss = ssb[b];
  float zz = zzb[b];
  float inv = 1.0f / ss;             // one IEEE div per block (uniform)
  const v4f* xin = (const v4f*)(x + (size_t)p * HW);
  v4f*       oq  = (v4f*)(out + (size_t)p * HW);
  int t = threadIdx.x;
  #pragma unroll
  for (int k = 0; k < 4; k++){
    v4f v = xin[t + 256 * k];
    float in[4] = {v.x, v.y, v.z, v.w};
    float r[4];
    #pragma unroll
    for (int i = 0; i < 4; i++){
      float o = sc * in[i];
      float q = fminf(fmaxf(rintf(__builtin_fmaf(o, inv, zz)), 0.f), 255.f);
      float f = (q - zz) * ss;
      r[i] = o + (f - o);   // reproduce ref's out + (fq - out) fp ordering
    }
    v4f res;
    res.x = r[0]; res.y = r[1]; res.z = r[2]; res.w = r[3];
    __builtin_nontemporal_store(res, oq + t + 256 * k);
  }
}

extern "C" void kernel_launch(void* const* d_in, const int* in_sizes, int n_in,
                              void* d_out, int out_size, void* d_ws, size_t ws_size,
                              hipStream_t stream) {
  const float* x  = (const float*)d_in[0];
  const float* w1 = (const float*)d_in[1];
  const float* b1 = (const float*)d_in[2];
  const float* w2 = (const float*)d_in[3];
  const float* b2 = (const float*)d_in[4];
  const float* ar = (const float*)d_in[5];
  const int* clus = (const int*)d_in[6];
  float* out = (float*)d_out;

  float* ws    = (float*)d_ws;
  float* sumb  = ws;            // 16384
  float* minb  = ws + BC;       // 16384
  float* maxb  = ws + 2 * BC;   // 16384
  float* scaleb= ws + 3 * BC;   // 16384
  float* ssb   = ws + 4 * BC;        // 64
  float* zzb   = ssb + B_;           // 64
  float* sminb = zzb + B_;           // 64
  float* smaxb = sminb + B_;         // 64

  hipLaunchKernelGGL(k_reduce, dim3(BC), dim3(256), 0, stream, x, sumb, minb, maxb);
  hipLaunchKernelGGL(k_mlp, dim3(B_), dim3(256), 0, stream,
                     sumb, minb, maxb, w1, b1, w2, b2, scaleb, sminb, smaxb);
  hipLaunchKernelGGL(k_cluster, dim3(1), dim3(64), 0, stream,
                     sminb, smaxb, ar, clus, ssb, zzb);
  hipLaunchKernelGGL(k_quant, dim3(BC), dim3(256), 0, stream, x, scaleb, ssb, zzb, out);
}

// Round 2
// 486.434 us; speedup vs baseline: 1.0483x; 1.0246x over previous
//
#include <hip/hip_runtime.h>

#define B_  64
#define C_  256
#define CS  64
#define NC  8
#define HW  4096
#define BC  16384   // B_*C_

typedef float v4f __attribute__((ext_vector_type(4)));

// ALL tensors fp32 (x, w1, b1, w2, b2, act_range fp32; sample_cluster int32; out fp32).

// Monotone bijection float -> uint32 (preserves total order) for atomic min/max.
__device__ __forceinline__ unsigned int enc_key(float f){
  unsigned int u = __float_as_uint(f);
  return (u & 0x80000000u) ? ~u : (u | 0x80000000u);
}
__device__ __forceinline__ float dec_key(unsigned int key){
  unsigned int u = (key & 0x80000000u) ? (key ^ 0x80000000u) : ~key;
  return __uint_as_float(u);
}

// ---------------- Kernel 1: per-(b,c) plane sum/min/max over HW ----------------
// Regular (caching) loads on purpose: we WANT x resident in L3 for k_quant's re-read.
// Block 0 additionally initializes the per-cluster atomic slots (ws is poisoned).
__global__ __launch_bounds__(256) void k_reduce(const float* __restrict__ x,
    float* __restrict__ sumb, float* __restrict__ minb, float* __restrict__ maxb,
    unsigned int* __restrict__ cmin_enc, unsigned int* __restrict__ cmax_enc){
  int p = blockIdx.x;
  int t = threadIdx.x;
  if (p == 0 && t < NC){
    cmin_enc[t] = 0xFF800000u;   // enc(+INF)
    cmax_enc[t] = 0x007FFFFFu;   // enc(-INF)
  }
  const float4* base = (const float4*)(x + (size_t)p * HW);
  float s = 0.f, mn = INFINITY, mx = -INFINITY;
  #pragma unroll
  for (int k = 0; k < 4; k++){
    float4 v = base[t + 256 * k];
    s += (v.x + v.y) + (v.z + v.w);
    mn = fminf(mn, fminf(fminf(v.x, v.y), fminf(v.z, v.w)));
    mx = fmaxf(mx, fmaxf(fmaxf(v.x, v.y), fmaxf(v.z, v.w)));
  }
  #pragma unroll
  for (int off = 1; off < 64; off <<= 1){
    s  += __shfl_xor(s, off, 64);
    mn  = fminf(mn, __shfl_xor(mn, off, 64));
    mx  = fmaxf(mx, __shfl_xor(mx, off, 64));
  }
  __shared__ float ls[4], lmn[4], lmx[4];
  int w = t >> 6;
  if ((t & 63) == 0){ ls[w] = s; lmn[w] = mn; lmx[w] = mx; }
  __syncthreads();
  if (t == 0){
    sumb[p] = ls[0] + ls[1] + ls[2] + ls[3];
    minb[p] = fminf(fminf(lmn[0], lmn[1]), fminf(lmn[2], lmn[3]));
    maxb[p] = fmaxf(fmaxf(lmx[0], lmx[1]), fmaxf(lmx[2], lmx[3]));
  }
}

// ---------------- Kernel 2: per-sample MLP + hardsigmoid + sample min/max ----------------
// grid = 64 blocks (one per batch sample), 256 threads (one per channel c).
// Tail: per-cluster segment min/max via device-scope atomics (replaces k_cluster).
__global__ __launch_bounds__(256) void k_mlp(
    const float* __restrict__ sumb, const float* __restrict__ minb, const float* __restrict__ maxb,
    const float* __restrict__ w1, const float* __restrict__ b1,
    const float* __restrict__ w2, const float* __restrict__ b2,
    const int* __restrict__ clus,
    float* __restrict__ scaleb,
    unsigned int* __restrict__ cmin_enc, unsigned int* __restrict__ cmax_enc){
  int b = blockIdx.x;
  int t = threadIdx.x;
  __shared__ float s_pool[C_];
  __shared__ float s_h[CS];
  __shared__ float lmn[4], lmx[4];

  s_pool[t] = sumb[b * C_ + t] * (1.0f / 4096.0f);   // pooled = sum/4096 (exact pow2)
  __syncthreads();

  if (t < CS){
    const float4* pw = (const float4*)(w1 + t * C_);
    const float4* pp = (const float4*)s_pool;
    float acc = 0.f;
    #pragma unroll
    for (int i = 0; i < 64; i++){
      float4 w = pw[i], p = pp[i];
      acc += p.x*w.x + p.y*w.y + p.z*w.z + p.w*w.w;
    }
    s_h[t] = fmaxf(acc + b1[t], 0.f);
  }
  __syncthreads();

  // channel c = t: scale = hardsigmoid(dot(h, w2[c]) + b2[c])
  const float4* pw2 = (const float4*)(w2 + t * CS);
  const float4* ph  = (const float4*)s_h;
  float acc = 0.f;
  #pragma unroll
  for (int i = 0; i < 16; i++){
    float4 w = pw2[i], h = ph[i];
    acc += h.x*w.x + h.y*w.y + h.z*w.z + h.w*w.w;
  }
  float v = acc + b2[t];
  float sc = fminf(fmaxf(v * (1.0f / 6.0f) + 0.5f, 0.f), 1.f);
  scaleb[b * C_ + t] = sc;

  // per-sample min/max of out = scale*x: scale>=0, fp32 mul monotone -> exact
  float mn = sc * minb[b * C_ + t];
  float mx = sc * maxb[b * C_ + t];
  #pragma unroll
  for (int off = 1; off < 64; off <<= 1){
    mn = fminf(mn, __shfl_xor(mn, off, 64));
    mx = fmaxf(mx, __shfl_xor(mx, off, 64));
  }
  int w = t >> 6;
  if ((t & 63) == 0){ lmn[w] = mn; lmx[w] = mx; }
  __syncthreads();
  if (t == 0){
    float smin = fminf(fminf(lmn[0], lmn[1]), fminf(lmn[2], lmn[3]));
    float smax = fmaxf(fmaxf(lmx[0], lmx[1]), fmaxf(lmx[2], lmx[3]));
    int k = clus[b];
    atomicMin(&cmin_enc[k], enc_key(smin));   // device-scope by default (G12)
    atomicMax(&cmax_enc[k], enc_key(smax));
  }
}

// ---------------- Kernel 3: elementwise fake-quant (fp32 in -> fp32 out) ----------------
// - 2 planes per block: 8 independent nt loads in flight per thread (MLP for any L3 misses).
// - REVERSE global plane order: read the L3-warmest planes first.
// - NON-TEMPORAL loads for x (last use: mark for early eviction) and nt stores for out
//   (never re-read: keep the write stream from evicting unread x lines).
// - ss/zz derived inline from the cluster atomic slots (identical uniform arithmetic in
//   every block -> identical bits; removes the k_cluster launch from the critical path).
__global__ __launch_bounds__(256) void k_quant(const float* __restrict__ x,
    const float* __restrict__ scaleb,
    const unsigned int* __restrict__ cmin_enc, const unsigned int* __restrict__ cmax_enc,
    const float* __restrict__ act_range, const int* __restrict__ clus,
    float* __restrict__ out){
  int p0 = (BC - 2) - 2 * (int)blockIdx.x;   // even; p0 and p0+1 share sample b
  int b  = p0 >> 8;
  int kcl = clus[b];
  float cm = dec_key(cmin_enc[kcl]);
  float cM = dec_key(cmax_enc[kcl]);
  float nmin = act_range[2*kcl]     * 0.995f + cm * 0.005f;
  float nmax = act_range[2*kcl + 1] * 0.995f + cM * 0.005f;
  float ss = (nmax - nmin) / 255.0f;
  float zz = -rintf(nmin / ss);       // rintf = round-half-even = jnp.round
  float inv = 1.0f / ss;              // one IEEE div per block (uniform)
  float sc0 = scaleb[p0];
  float sc1 = scaleb[p0 + 1];

  const v4f* x0 = (const v4f*)(x + (size_t)p0 * HW);
  const v4f* x1 = x0 + (HW / 4);
  v4f* o0 = (v4f*)(out + (size_t)p0 * HW);
  v4f* o1 = o0 + (HW / 4);
  int t = threadIdx.x;

  v4f va[4], vb[4];
  #pragma unroll
  for (int k = 0; k < 4; k++) va[k] = __builtin_nontemporal_load(x0 + t + 256 * k);
  #pragma unroll
  for (int k = 0; k < 4; k++) vb[k] = __builtin_nontemporal_load(x1 + t + 256 * k);

  #pragma unroll
  for (int k = 0; k < 4; k++){
    v4f res;
    #pragma unroll
    for (int i = 0; i < 4; i++){
      float o = sc0 * va[k][i];
      float q = fminf(fmaxf(rintf(__builtin_fmaf(o, inv, zz)), 0.f), 255.f);
      float f = (q - zz) * ss;
      res[i] = o + (f - o);   // reproduce ref's out + (fq - out) fp ordering
    }
    __builtin_nontemporal_store(res, o0 + t + 256 * k);
  }
  #pragma unroll
  for (int k = 0; k < 4; k++){
    v4f res;
    #pragma unroll
    for (int i = 0; i < 4; i++){
      float o = sc1 * vb[k][i];
      float q = fminf(fmaxf(rintf(__builtin_fmaf(o, inv, zz)), 0.f), 255.f);
      float f = (q - zz) * ss;
      res[i] = o + (f - o);
    }
    __builtin_nontemporal_store(res, o1 + t + 256 * k);
  }
}

extern "C" void kernel_launch(void* const* d_in, const int* in_sizes, int n_in,
                              void* d_out, int out_size, void* d_ws, size_t ws_size,
                              hipStream_t stream) {
  const float* x  = (const float*)d_in[0];
  const float* w1 = (const float*)d_in[1];
  const float* b1 = (const float*)d_in[2];
  const float* w2 = (const float*)d_in[3];
  const float* b2 = (const float*)d_in[4];
  const float* ar = (const float*)d_in[5];
  const int* clus = (const int*)d_in[6];
  float* out = (float*)d_out;

  float* ws    = (float*)d_ws;
  float* sumb  = ws;            // 16384
  float* minb  = ws + BC;       // 16384
  float* maxb  = ws + 2 * BC;   // 16384
  float* scaleb= ws + 3 * BC;   // 16384
  unsigned int* cmin_enc = (unsigned int*)(ws + 4 * BC);  // 8
  unsigned int* cmax_enc = cmin_enc + NC;                 // 8

  hipLaunchKernelGGL(k_reduce, dim3(BC), dim3(256), 0, stream,
                     x, sumb, minb, maxb, cmin_enc, cmax_enc);
  hipLaunchKernelGGL(k_mlp, dim3(B_), dim3(256), 0, stream,
                     sumb, minb, maxb, w1, b1, w2, b2, clus, scaleb, cmin_enc, cmax_enc);
  hipLaunchKernelGGL(k_quant, dim3(BC / 2), dim3(256), 0, stream,
                     x, scaleb, cmin_enc, cmax_enc, ar, clus, out);
}